// Round 1
// baseline (112.844 us; speedup 1.0000x reference)
//
#include <hip/hip_runtime.h>
#include <hip/hip_bf16.h>

#define B_ROWS 4096
#define DIMN 128
#define N2 8192
#define CEXP 2.8853900817779268f  // log2(e)/TEMP, TEMP=0.5

using short8 = __attribute__((ext_vector_type(8))) short;
using f32x4  = __attribute__((ext_vector_type(4))) float;

// --- 1. L2-normalize each row of [emb_i; emb_j] and cast to bf16 ------------
__global__ void normalize_k(const float* __restrict__ emb_i,
                            const float* __restrict__ emb_j,
                            __hip_bfloat162* __restrict__ zb2) {
    int row  = blockIdx.x * 4 + (threadIdx.x >> 6);
    int lane = threadIdx.x & 63;
    const float2* src = (const float2*)(row < B_ROWS
                          ? emb_i + (size_t)row * DIMN
                          : emb_j + (size_t)(row - B_ROWS) * DIMN);
    float2 v = src[lane];
    float ss = v.x * v.x + v.y * v.y;
    #pragma unroll
    for (int m = 32; m; m >>= 1) ss += __shfl_xor(ss, m);
    float inv = 1.0f / fmaxf(sqrtf(ss), 1e-12f);
    __hip_bfloat162 o;
    o.x = __float2bfloat16(v.x * inv);
    o.y = __float2bfloat16(v.y * inv);
    zb2[(size_t)row * 64 + lane] = o;
}

// --- 2. positives: sum_k dot(z_i[k], z_j[k]) --------------------------------
__global__ void pos_k(const __hip_bfloat162* __restrict__ zb2,
                      float* __restrict__ possum) {
    int lane = threadIdx.x & 63;
    int w    = threadIdx.x >> 6;
    float acc = 0.f;
    for (int i = 0; i < 16; ++i) {
        int k = (blockIdx.x * 4 + w) * 16 + i;
        __hip_bfloat162 a = zb2[(size_t)k * 64 + lane];
        __hip_bfloat162 b = zb2[(size_t)(k + B_ROWS) * 64 + lane];
        acc += __bfloat162float(a.x) * __bfloat162float(b.x)
             + __bfloat162float(a.y) * __bfloat162float(b.y);
    }
    #pragma unroll
    for (int m = 32; m; m >>= 1) acc += __shfl_xor(acc, m);
    __shared__ float red[4];
    if (lane == 0) red[w] = acc;
    __syncthreads();
    if (threadIdx.x == 0) atomicAdd(possum, red[0] + red[1] + red[2] + red[3]);
}

// --- 3. fused Gram GEMM + exp + row-sum -------------------------------------
// 128x128 output tile per block, 4 waves (2x2 of 64x64), K=128 (4 MFMA k-steps)
__global__ __launch_bounds__(256) void gemm_k(const __hip_bfloat16* __restrict__ zb,
                                              float* __restrict__ rowsum) {
    __shared__ short As[128][136];   // +8 shorts (16B) pad: 272B stride, 2-way bank alias (free)
    __shared__ short Bs[128][136];
    const int tid = threadIdx.x;
    const int bx = blockIdx.x, by = blockIdx.y;
    const short* z = (const short*)zb;

    // stage: 128 rows x 256B each, 16B per chunk, 2048 chunks per tile
    {
        const uint4* ga = (const uint4*)(z + (size_t)by * 128 * 128);
        const uint4* gb = (const uint4*)(z + (size_t)bx * 128 * 128);
        #pragma unroll
        for (int i = 0; i < 8; ++i) {
            int c = tid + i * 256;
            int r = c >> 4, s = c & 15;
            *(uint4*)&As[r][s * 8] = ga[c];
            *(uint4*)&Bs[r][s * 8] = gb[c];
        }
    }
    __syncthreads();

    const int lane = tid & 63;
    const int w = tid >> 6, wr = w >> 1, wc = w & 1;
    const int fr = lane & 15;
    const int kh = (lane >> 4) * 8;

    f32x4 acc[4][4] = {};
    #pragma unroll
    for (int kk = 0; kk < 4; ++kk) {
        const int kb = kk * 32 + kh;
        short8 af[4], bf[4];
        #pragma unroll
        for (int m = 0; m < 4; ++m)
            af[m] = *(const short8*)&As[wr * 64 + m * 16 + fr][kb];
        #pragma unroll
        for (int n = 0; n < 4; ++n)
            bf[n] = *(const short8*)&Bs[wc * 64 + n * 16 + fr][kb];
        #pragma unroll
        for (int m = 0; m < 4; ++m)
            #pragma unroll
            for (int n = 0; n < 4; ++n)
                acc[m][n] = __builtin_amdgcn_mfma_f32_16x16x32_bf16(
                    af[m], bf[n], acc[m][n], 0, 0, 0);
    }

    // epilogue: e = exp2(sim * log2e/T), zero diagonal, reduce over cols
    const int rbase = by * 128 + wr * 64;
    const int cbase = bx * 128 + wc * 64;
    const int rq = (lane >> 4) * 4;
    #pragma unroll
    for (int m = 0; m < 4; ++m) {
        const int row = rbase + m * 16 + rq;   // rows row..row+3 (C/D: row=(lane>>4)*4+reg)
        float s0 = 0.f, s1 = 0.f, s2 = 0.f, s3 = 0.f;
        #pragma unroll
        for (int n = 0; n < 4; ++n) {
            const int col = cbase + n * 16 + fr;  // C/D: col = lane&15
            float e0 = exp2f(acc[m][n][0] * CEXP);
            float e1 = exp2f(acc[m][n][1] * CEXP);
            float e2 = exp2f(acc[m][n][2] * CEXP);
            float e3 = exp2f(acc[m][n][3] * CEXP);
            if (row + 0 == col) e0 = 0.f;
            if (row + 1 == col) e1 = 0.f;
            if (row + 2 == col) e2 = 0.f;
            if (row + 3 == col) e3 = 0.f;
            s0 += e0; s1 += e1; s2 += e2; s3 += e3;
        }
        #pragma unroll
        for (int d = 1; d < 16; d <<= 1) {
            s0 += __shfl_xor(s0, d);
            s1 += __shfl_xor(s1, d);
            s2 += __shfl_xor(s2, d);
            s3 += __shfl_xor(s3, d);
        }
        if (fr == 0) {
            atomicAdd(&rowsum[row + 0], s0);
            atomicAdd(&rowsum[row + 1], s1);
            atomicAdd(&rowsum[row + 2], s2);
            atomicAdd(&rowsum[row + 3], s3);
        }
    }
}

// --- 4. finalize: loss = (sum log(denom) - (2/T) * possum) / (2B*5) ---------
__global__ void finalize_k(const float* __restrict__ rowsum,
                           const float* __restrict__ scal,
                           float* __restrict__ out) {
    float acc = 0.f;
    for (int r = threadIdx.x; r < N2; r += 256) acc += logf(rowsum[r]);
    #pragma unroll
    for (int m = 32; m; m >>= 1) acc += __shfl_xor(acc, m);
    __shared__ float red[4];
    if ((threadIdx.x & 63) == 0) red[threadIdx.x >> 6] = acc;
    __syncthreads();
    if (threadIdx.x == 0) {
        float logsum = red[0] + red[1] + red[2] + red[3];
        // positives appear twice (sim_ij and sim_ji are equal): 2*possum / T = 4*possum
        out[0] = (logsum - 4.0f * scal[0]) / (float)(2 * B_ROWS * 5);
    }
}

extern "C" void kernel_launch(void* const* d_in, const int* in_sizes, int n_in,
                              void* d_out, int out_size, void* d_ws, size_t ws_size,
                              hipStream_t stream) {
    const float* emb_i = (const float*)d_in[0];
    const float* emb_j = (const float*)d_in[1];
    __hip_bfloat16* zb = (__hip_bfloat16*)d_ws;                       // 2 MB bf16 Z
    float* rowsum = (float*)((char*)d_ws + (size_t)N2 * DIMN * 2);    // 32 KB
    float* scal   = rowsum + N2;                                      // possum

    hipMemsetAsync(rowsum, 0, N2 * sizeof(float) + 16, stream);
    normalize_k<<<N2 / 4, 256, 0, stream>>>(emb_i, emb_j, (__hip_bfloat162*)zb);
    pos_k<<<64, 256, 0, stream>>>((const __hip_bfloat162*)zb, scal);
    gemm_k<<<dim3(64, 64), 256, 0, stream>>>(zb, rowsum);
    finalize_k<<<1, 256, 0, stream>>>(rowsum, scal, (float*)d_out);
}

// Round 2
// 77.713 us; speedup vs baseline: 1.4521x; 1.4521x over previous
//
#include <hip/hip_runtime.h>
#include <hip/hip_bf16.h>

#define B_ROWS 4096
#define DIMN 128
#define N2 8192
#define NT 128            // 8192 / 64 tiles per side
#define NTILES 8256       // NT*(NT+1)/2
#define CEXP 2.8853900817779268f  // log2(e)/TEMP, TEMP=0.5

using short8 = __attribute__((ext_vector_type(8))) short;
using f32x4  = __attribute__((ext_vector_type(4))) float;

// --- 1. fused: L2-normalize rows -> bf16 Z, and positives partial dots ------
__global__ void normpos_k(const float* __restrict__ emb_i,
                          const float* __restrict__ emb_j,
                          __hip_bfloat162* __restrict__ zb2,
                          float* __restrict__ pospart) {
    int w    = threadIdx.x >> 6;
    int lane = threadIdx.x & 63;
    int pair = blockIdx.x * 4 + w;          // 0..4095
    float2 a = ((const float2*)(emb_i + (size_t)pair * DIMN))[lane];
    float2 b = ((const float2*)(emb_j + (size_t)pair * DIMN))[lane];
    float sa = a.x * a.x + a.y * a.y;
    float sb = b.x * b.x + b.y * b.y;
    float dp = a.x * b.x + a.y * b.y;
    #pragma unroll
    for (int m = 32; m; m >>= 1) {
        sa += __shfl_xor(sa, m);
        sb += __shfl_xor(sb, m);
        dp += __shfl_xor(dp, m);
    }
    float ia = 1.0f / fmaxf(sqrtf(sa), 1e-12f);
    float ib = 1.0f / fmaxf(sqrtf(sb), 1e-12f);
    __hip_bfloat162 oa, ob;
    oa.x = __float2bfloat16(a.x * ia); oa.y = __float2bfloat16(a.y * ia);
    ob.x = __float2bfloat16(b.x * ib); ob.y = __float2bfloat16(b.y * ib);
    zb2[(size_t)pair * 64 + lane] = oa;
    zb2[(size_t)(pair + B_ROWS) * 64 + lane] = ob;
    __shared__ float red[4];
    if (lane == 0) red[w] = dp * ia * ib;
    __syncthreads();
    if (threadIdx.x == 0)
        pospart[blockIdx.x] = red[0] + red[1] + red[2] + red[3];
}

// --- 2. symmetric fused Gram GEMM + exp + row/col sums ----------------------
// 1 wave = one 64x64 upper-triangular tile, fragments loaded straight from L2.
__global__ __launch_bounds__(256) void gemm_k(const __hip_bfloat16* __restrict__ zb,
                                              float* __restrict__ rowsum) {
    const int lane = threadIdx.x & 63;
    const int t = blockIdx.x * 4 + (threadIdx.x >> 6);   // tile id, 0..8255
    // invert upper-tri row-major enumeration: offset(r) = 128r - r(r-1)/2
    int tr = (int)((257.0f - sqrtf(66049.0f - 8.0f * (float)t)) * 0.5f);
    if (tr > NT - 1) tr = NT - 1;
    while (tr > 0 && 128 * tr - (tr * (tr - 1)) / 2 > t) --tr;
    while (128 * (tr + 1) - ((tr + 1) * tr) / 2 <= t) ++tr;
    const int tc = tr + t - (128 * tr - (tr * (tr - 1)) / 2);

    const short* z = (const short*)zb;
    const int R0 = tr * 64, C0 = tc * 64;
    const int fr = lane & 15;
    const int kh = (lane >> 4) * 8;

    f32x4 acc[4][4] = {};
    #pragma unroll
    for (int kk = 0; kk < 4; ++kk) {
        const int kb = kk * 32 + kh;
        short8 af[4], bf[4];
        #pragma unroll
        for (int m = 0; m < 4; ++m)
            af[m] = *(const short8*)(z + (R0 + m * 16 + fr) * DIMN + kb);
        #pragma unroll
        for (int n = 0; n < 4; ++n)
            bf[n] = *(const short8*)(z + (C0 + n * 16 + fr) * DIMN + kb);
        #pragma unroll
        for (int m = 0; m < 4; ++m)
            #pragma unroll
            for (int n = 0; n < 4; ++n)
                acc[m][n] = __builtin_amdgcn_mfma_f32_16x16x32_bf16(
                    af[m], bf[n], acc[m][n], 0, 0, 0);
    }

    // epilogue: e = exp2(sim*CEXP); diag tiles zero the diagonal (row sums only);
    // off-diag tiles contribute to row sums AND (by symmetry) column sums.
    const int rq = (lane >> 4) * 4;
    const bool diag = (tr == tc);
    float cacc[4] = {0.f, 0.f, 0.f, 0.f};
    #pragma unroll
    for (int m = 0; m < 4; ++m) {
        const int row = R0 + m * 16 + rq;     // C/D: row = (lane>>4)*4 + reg
        float s0 = 0.f, s1 = 0.f, s2 = 0.f, s3 = 0.f;
        #pragma unroll
        for (int n = 0; n < 4; ++n) {
            const int col = C0 + n * 16 + fr; // C/D: col = lane&15
            float e0 = exp2f(acc[m][n][0] * CEXP);
            float e1 = exp2f(acc[m][n][1] * CEXP);
            float e2 = exp2f(acc[m][n][2] * CEXP);
            float e3 = exp2f(acc[m][n][3] * CEXP);
            if (diag) {
                if (row + 0 == col) e0 = 0.f;
                if (row + 1 == col) e1 = 0.f;
                if (row + 2 == col) e2 = 0.f;
                if (row + 3 == col) e3 = 0.f;
            }
            s0 += e0; s1 += e1; s2 += e2; s3 += e3;
            cacc[n] += e0 + e1 + e2 + e3;
        }
        #pragma unroll
        for (int d = 1; d < 16; d <<= 1) {
            s0 += __shfl_xor(s0, d);
            s1 += __shfl_xor(s1, d);
            s2 += __shfl_xor(s2, d);
            s3 += __shfl_xor(s3, d);
        }
        if (fr == 0) {
            atomicAdd(&rowsum[row + 0], s0);
            atomicAdd(&rowsum[row + 1], s1);
            atomicAdd(&rowsum[row + 2], s2);
            atomicAdd(&rowsum[row + 3], s3);
        }
    }
    if (!diag) {
        #pragma unroll
        for (int n = 0; n < 4; ++n) {
            cacc[n] += __shfl_xor(cacc[n], 16);
            cacc[n] += __shfl_xor(cacc[n], 32);
        }
        if (rq == 0) {   // lanes 0..15 hold col sums for col C0 + n*16 + fr
            #pragma unroll
            for (int n = 0; n < 4; ++n)
                atomicAdd(&rowsum[C0 + n * 16 + fr], cacc[n]);
        }
    }
}

// --- 3. finalize: loss = (sum log(denom) - 4 * sum(pos)) / (2B*5) -----------
__global__ void finalize_k(const float* __restrict__ rowsum,
                           const float* __restrict__ pospart,
                           float* __restrict__ out) {
    float acc = 0.f;
    for (int r = threadIdx.x; r < N2; r += 256) acc += logf(rowsum[r]);
    float pp = 0.f;
    for (int r = threadIdx.x; r < 1024; r += 256) pp += pospart[r];
    acc -= 4.0f * pp;
    #pragma unroll
    for (int m = 32; m; m >>= 1) acc += __shfl_xor(acc, m);
    __shared__ float red[4];
    if ((threadIdx.x & 63) == 0) red[threadIdx.x >> 6] = acc;
    __syncthreads();
    if (threadIdx.x == 0)
        out[0] = (red[0] + red[1] + red[2] + red[3]) / (float)(2 * B_ROWS * 5);
}

extern "C" void kernel_launch(void* const* d_in, const int* in_sizes, int n_in,
                              void* d_out, int out_size, void* d_ws, size_t ws_size,
                              hipStream_t stream) {
    const float* emb_i = (const float*)d_in[0];
    const float* emb_j = (const float*)d_in[1];
    __hip_bfloat16* zb = (__hip_bfloat16*)d_ws;                       // 2 MB bf16 Z
    float* rowsum  = (float*)((char*)d_ws + (size_t)N2 * DIMN * 2);   // 32 KB
    float* pospart = rowsum + N2;                                     // 4 KB

    hipMemsetAsync(rowsum, 0, N2 * sizeof(float), stream);
    normpos_k<<<1024, 256, 0, stream>>>(emb_i, emb_j, (__hip_bfloat162*)zb, pospart);
    gemm_k<<<NTILES / 4, 256, 0, stream>>>(zb, rowsum);
    finalize_k<<<1, 256, 0, stream>>>(rowsum, pospart, (float*)d_out);
}